// Round 11
// baseline (169.435 us; speedup 1.0000x reference)
//
#include <hip/hip_runtime.h>

#define NPTS   8192
#define BLOCK  256
#define IR     2                    // i's per thread (register tile)
#define IBSZ   (64*IR)              // 128 distinct i's per block
#define NIB    (NPTS/IBSZ)          // 64 i-blocks
#define JS     32                   // grid-level j splits
#define JBLK   (NPTS/JS)            // 256 j's staged per block
#define NPAIR  (JBLK/2)             // 128 packed pairs
#define WPAIR  (NPAIR/4)            // 32 pairs per wave (64 j's)

// Pre-scale trick: with S = sqrt(100*log2(e)), exp(-100*d2) = exp2(-|S(qi-qj)|^2).
#define SCALE  12.01122409f
// Output-0 scale: aa accumulates w*S*dx, so final factor = 400/S.
#define A_SCALE (400.0f / 12.01122409f)

__global__ __launch_bounds__(BLOCK, 8) void lddmm_hamilton_kernel(
    const float* __restrict__ mom,  // [N,3]
    const float* __restrict__ q,    // [N,3]
    float* __restrict__ out)        // [2,N,3]
{
    __shared__ float4 st[3 * NPAIR];   // 6 KiB: packed j pairs (q pre-scaled)
    __shared__ float  pr[6 * IBSZ];    // 3 KiB: partial[c][ilocal], ds_add reduced

    const int tid = threadIdx.x;
    const int ib  = blockIdx.x & (NIB - 1);   // 0..63
    const int jsg = blockIdx.x >> 6;          // 0..31
    const int wv  = tid >> 6;                 // wave id = j-quarter
    const int il  = tid & 63;
    const int j0  = jsg * JBLK;

    // zero the LDS partials (poisoned between runs)
    #pragma unroll
    for (int k = tid; k < 6 * IBSZ; k += BLOCK) pr[k] = 0.f;

    // stage 256 j's as packed pairs; q components pre-scaled by SCALE
    if (tid < NPAIR) {
        const float* qa = q   + 3 * (j0 + 2 * tid);  // qx0 qy0 qz0 qx1 qy1 qz1
        const float* pa = mom + 3 * (j0 + 2 * tid);
        st[tid]           = make_float4(qa[0]*SCALE, qa[3]*SCALE, qa[1]*SCALE, qa[4]*SCALE);
        st[NPAIR   + tid] = make_float4(qa[2]*SCALE, qa[5]*SCALE, pa[0], pa[3]);
        st[2*NPAIR + tid] = make_float4(pa[1], pa[4], pa[2], pa[5]);
    }

    // per-thread register tile of 2 i's (q pre-scaled)
    float qi[IR][3], pi[IR][3];
    #pragma unroll
    for (int r = 0; r < IR; ++r) {
        const int i = ib * IBSZ + il + 64 * r;
        qi[r][0] = q[3*i+0]*SCALE; qi[r][1] = q[3*i+1]*SCALE; qi[r][2] = q[3*i+2]*SCALE;
        pi[r][0] = mom[3*i+0];     pi[r][1] = mom[3*i+1];     pi[r][2] = mom[3*i+2];
    }

    float aa[IR][3] = {{0}}, mm[IR][3] = {{0}};

    __syncthreads();

    const int p0 = wv * WPAIR;
    #pragma unroll 4
    for (int p = 0; p < WPAIR; ++p) {
        const float4 A = st[p0 + p];             // wave-uniform broadcast b128
        const float4 B = st[NPAIR + p0 + p];
        const float4 C = st[2*NPAIR + p0 + p];
        // even j: q=(A.x,A.z,B.x) p=(B.z,C.x,C.z); odd j: q=(A.y,A.w,B.y) p=(B.w,C.y,C.w)
        #pragma unroll
        for (int r = 0; r < IR; ++r) {
            {   // even j
                const float dx = qi[r][0] - A.x;
                const float dy = qi[r][1] - A.z;
                const float dz = qi[r][2] - B.x;
                const float d2 = dx*dx + dy*dy + dz*dz;       // scaled: S^2*|qi-qj|^2
                float K;                                      // K = exp2(-d2)
                asm("v_exp_f32 %0, -%1" : "=v"(K) : "v"(d2));
                const float dt = pi[r][0]*B.z + pi[r][1]*C.x + pi[r][2]*C.z;
                mm[r][0] += K * B.z;  mm[r][1] += K * C.x;  mm[r][2] += K * C.z;
                const float w = K * dt;
                aa[r][0] += w * dx;   aa[r][1] += w * dy;   aa[r][2] += w * dz;
            }
            {   // odd j
                const float dx = qi[r][0] - A.y;
                const float dy = qi[r][1] - A.w;
                const float dz = qi[r][2] - B.y;
                const float d2 = dx*dx + dy*dy + dz*dz;
                float K;
                asm("v_exp_f32 %0, -%1" : "=v"(K) : "v"(d2));
                const float dt = pi[r][0]*B.w + pi[r][1]*C.y + pi[r][2]*C.w;
                mm[r][0] += K * B.w;  mm[r][1] += K * C.y;  mm[r][2] += K * C.w;
                const float w = K * dt;
                aa[r][0] += w * dx;   aa[r][1] += w * dy;   aa[r][2] += w * dz;
            }
        }
    }

    // cross-wave reduce via LDS float atomics (conflict-free: stride-1 across lanes)
    #pragma unroll
    for (int r = 0; r < IR; ++r) {
        const int ilocal = il + 64 * r;
        atomicAdd(&pr[0*IBSZ + ilocal], aa[r][0]);
        atomicAdd(&pr[1*IBSZ + ilocal], aa[r][1]);
        atomicAdd(&pr[2*IBSZ + ilocal], aa[r][2]);
        atomicAdd(&pr[3*IBSZ + ilocal], mm[r][0]);
        atomicAdd(&pr[4*IBSZ + ilocal], mm[r][1]);
        atomicAdd(&pr[5*IBSZ + ilocal], mm[r][2]);
    }
    __syncthreads();

    // readout: one thread per i, 6 global atomics
    if (tid < IBSZ) {
        const int i = ib * IBSZ + tid;
        atomicAdd(&out[3*i + 0],          A_SCALE * pr[0*IBSZ + tid]);
        atomicAdd(&out[3*i + 1],          A_SCALE * pr[1*IBSZ + tid]);
        atomicAdd(&out[3*i + 2],          A_SCALE * pr[2*IBSZ + tid]);
        atomicAdd(&out[3*NPTS + 3*i + 0], 2.0f    * pr[3*IBSZ + tid]);
        atomicAdd(&out[3*NPTS + 3*i + 1], 2.0f    * pr[4*IBSZ + tid]);
        atomicAdd(&out[3*NPTS + 3*i + 2], 2.0f    * pr[5*IBSZ + tid]);
    }
}

extern "C" void kernel_launch(void* const* d_in, const int* in_sizes, int n_in,
                              void* d_out, int out_size, void* d_ws, size_t ws_size,
                              hipStream_t stream) {
    const float* mom = (const float*)d_in[0];   // setup_inputs order: mom first
    const float* q   = (const float*)d_in[1];   // then control_points
    float* out = (float*)d_out;

    // d_out is re-poisoned to 0xAA before every timed launch; atomics need zeros.
    hipMemsetAsync(out, 0, (size_t)out_size * sizeof(float), stream);

    const dim3 grid(NIB * JS);                  // 64*32 = 2048 blocks, 8/CU resident
    lddmm_hamilton_kernel<<<grid, BLOCK, 0, stream>>>(mom, q, out);
}

// Round 16
// 122.401 us; speedup vs baseline: 1.3843x; 1.3843x over previous
//
#include <hip/hip_runtime.h>

#define NPTS   8192
#define BLOCK  256
#define IR     2                    // i's per thread (register tile)
#define IBSZ   (64*IR)              // 128 distinct i's per block
#define NIB    (NPTS/IBSZ)          // 64 i-blocks
#define JS     32                   // grid-level j splits
#define JBLK   (NPTS/JS)            // 256 j's staged per block
#define NPAIR  (JBLK/2)             // 128 packed pairs
#define WPAIR  (NPAIR/4)            // 32 pairs per wave (64 j's)

// Pre-scale trick: with S = sqrt(100*log2(e)), exp(-100*d2) = exp2(-|S(qi-qj)|^2).
#define SCALE  12.01122409f
// Output-0 scale: aa accumulates w*S*dx, so final factor = 400/S.
#define A_SCALE (400.0f / 12.01122409f)

#if __has_builtin(__builtin_amdgcn_exp2f)
#define EXP2(x) __builtin_amdgcn_exp2f(x)
#else
#define EXP2(x) exp2f(x)
#endif

__global__ __launch_bounds__(BLOCK, 4) void lddmm_hamilton_kernel(
    const float* __restrict__ mom,  // [N,3]
    const float* __restrict__ q,    // [N,3]
    float* __restrict__ out)        // [2,N,3]
{
    __shared__ float4 st[3 * NPAIR];   // 6 KiB: packed j pairs (q pre-scaled)
    __shared__ float  pr[6 * IBSZ];    // 3 KiB: partial[c][ilocal], ds_add reduced

    const int tid = threadIdx.x;
    const int ib  = blockIdx.x & (NIB - 1);   // 0..63
    const int jsg = blockIdx.x >> 6;          // 0..31
    const int wv  = tid >> 6;                 // wave id = j-quarter
    const int il  = tid & 63;
    const int j0  = jsg * JBLK;

    // zero the LDS partials (poisoned between runs)
    for (int k = tid; k < 6 * IBSZ; k += BLOCK) pr[k] = 0.f;

    // stage 256 j's as packed pairs; q components pre-scaled by SCALE
    if (tid < NPAIR) {
        const float* qa = q   + 3 * (j0 + 2 * tid);  // qx0 qy0 qz0 qx1 qy1 qz1
        const float* pa = mom + 3 * (j0 + 2 * tid);
        st[tid]           = make_float4(qa[0]*SCALE, qa[3]*SCALE, qa[1]*SCALE, qa[4]*SCALE);
        st[NPAIR   + tid] = make_float4(qa[2]*SCALE, qa[5]*SCALE, pa[0], pa[3]);
        st[2*NPAIR + tid] = make_float4(pa[1], pa[4], pa[2], pa[5]);
    }

    // per-thread register tile of 2 i's (q pre-scaled)
    float qi[IR][3], pi[IR][3];
    #pragma unroll
    for (int r = 0; r < IR; ++r) {
        const int i = ib * IBSZ + il + 64 * r;
        qi[r][0] = q[3*i+0]*SCALE; qi[r][1] = q[3*i+1]*SCALE; qi[r][2] = q[3*i+2]*SCALE;
        pi[r][0] = mom[3*i+0];     pi[r][1] = mom[3*i+1];     pi[r][2] = mom[3*i+2];
    }

    float aa[IR][3] = {{0}}, mm[IR][3] = {{0}};

    __syncthreads();

    const int p0 = wv * WPAIR;
    #pragma unroll 4
    for (int p = 0; p < WPAIR; ++p) {
        const float4 A = st[p0 + p];             // wave-uniform broadcast b128
        const float4 B = st[NPAIR + p0 + p];
        const float4 C = st[2*NPAIR + p0 + p];
        // even j: q=(A.x,A.z,B.x) p=(B.z,C.x,C.z); odd j: q=(A.y,A.w,B.y) p=(B.w,C.y,C.w)
        #pragma unroll
        for (int r = 0; r < IR; ++r) {
            {   // even j
                const float dx = qi[r][0] - A.x;
                const float dy = qi[r][1] - A.z;
                const float dz = qi[r][2] - B.x;
                const float d2 = dx*dx + dy*dy + dz*dz;       // scaled: S^2*|qi-qj|^2
                const float K  = EXP2(-d2);                   // v_exp_f32 w/ neg modifier
                const float dt = pi[r][0]*B.z + pi[r][1]*C.x + pi[r][2]*C.z;
                mm[r][0] += K * B.z;  mm[r][1] += K * C.x;  mm[r][2] += K * C.z;
                const float w = K * dt;
                aa[r][0] += w * dx;   aa[r][1] += w * dy;   aa[r][2] += w * dz;
            }
            {   // odd j
                const float dx = qi[r][0] - A.y;
                const float dy = qi[r][1] - A.w;
                const float dz = qi[r][2] - B.y;
                const float d2 = dx*dx + dy*dy + dz*dz;
                const float K  = EXP2(-d2);
                const float dt = pi[r][0]*B.w + pi[r][1]*C.y + pi[r][2]*C.w;
                mm[r][0] += K * B.w;  mm[r][1] += K * C.y;  mm[r][2] += K * C.w;
                const float w = K * dt;
                aa[r][0] += w * dx;   aa[r][1] += w * dy;   aa[r][2] += w * dz;
            }
        }
    }

    // cross-wave reduce via LDS float atomics (conflict-free: stride-1 across lanes)
    #pragma unroll
    for (int r = 0; r < IR; ++r) {
        const int ilocal = il + 64 * r;
        atomicAdd(&pr[0*IBSZ + ilocal], aa[r][0]);
        atomicAdd(&pr[1*IBSZ + ilocal], aa[r][1]);
        atomicAdd(&pr[2*IBSZ + ilocal], aa[r][2]);
        atomicAdd(&pr[3*IBSZ + ilocal], mm[r][0]);
        atomicAdd(&pr[4*IBSZ + ilocal], mm[r][1]);
        atomicAdd(&pr[5*IBSZ + ilocal], mm[r][2]);
    }
    __syncthreads();

    // readout: one thread per i, 6 global atomics
    if (tid < IBSZ) {
        const int i = ib * IBSZ + tid;
        atomicAdd(&out[3*i + 0],          A_SCALE * pr[0*IBSZ + tid]);
        atomicAdd(&out[3*i + 1],          A_SCALE * pr[1*IBSZ + tid]);
        atomicAdd(&out[3*i + 2],          A_SCALE * pr[2*IBSZ + tid]);
        atomicAdd(&out[3*NPTS + 3*i + 0], 2.0f    * pr[3*IBSZ + tid]);
        atomicAdd(&out[3*NPTS + 3*i + 1], 2.0f    * pr[4*IBSZ + tid]);
        atomicAdd(&out[3*NPTS + 3*i + 2], 2.0f    * pr[5*IBSZ + tid]);
    }
}

extern "C" void kernel_launch(void* const* d_in, const int* in_sizes, int n_in,
                              void* d_out, int out_size, void* d_ws, size_t ws_size,
                              hipStream_t stream) {
    const float* mom = (const float*)d_in[0];   // setup_inputs order: mom first
    const float* q   = (const float*)d_in[1];   // then control_points
    float* out = (float*)d_out;

    // d_out is re-poisoned to 0xAA before every timed launch; atomics need zeros.
    hipMemsetAsync(out, 0, (size_t)out_size * sizeof(float), stream);

    const dim3 grid(NIB * JS);                  // 64*32 = 2048 blocks, 8/CU
    lddmm_hamilton_kernel<<<grid, BLOCK, 0, stream>>>(mom, q, out);
}